// Round 16
// baseline (425.116 us; speedup 1.0000x reference)
//
#include <hip/hip_runtime.h>

// ---------------------------------------------------------------------------
// LinearAttention (Linformer-style) on MI355X, bf16 MFMA pipeline, f32 accum.
// B=4 S=4096 D=1024 H=16 R=256 DK=64
// Round 16: launch-count diet on the r10/r15 baseline (384 us). No schedule
//           changes. (1) QKV GEMM grouped: one dispatch loops the proven r8
//           body over q/k/v members; (2) weight converts 4->1, activation
//           converts 3->1 (grid.y select); (3) kpvp pair 2->1 (grid.z parity).
//           15 -> 9 dispatches.
// ---------------------------------------------------------------------------

typedef __bf16 bf16;
typedef bf16 bf16x8 __attribute__((ext_vector_type(8)));
typedef bf16 bf16x4 __attribute__((ext_vector_type(4)));
typedef float f32x4 __attribute__((ext_vector_type(4)));

constexpr int BB = 4, SS = 4096, DD = 1024, HH = 16, RR = 256, DK = 64;

// q-projection output pre-scale: logits*log2e/8 so softmax uses exp2 directly
#define QSCALE 0.1803368801111204f

// async global->LDS, 16B per lane. ldsbase must be wave-uniform; HW writes
// lane l's 16B at ldsbase + l*16. gptr is per-lane.
__device__ __forceinline__ void gl2lds16(const void* g, void* l, int lane)
{
#if __has_builtin(__builtin_amdgcn_global_load_lds)
    auto gp = reinterpret_cast<const __attribute__((address_space(1))) void*>(
        reinterpret_cast<uintptr_t>(g));
    auto lp = reinterpret_cast<__attribute__((address_space(3))) void*>(
        reinterpret_cast<uintptr_t>(l));
    __builtin_amdgcn_global_load_lds(gp, lp, 16, 0, 0);
    (void)lane;
#else
    *(bf16x8*)((char*)l + lane * 16) = *(const bf16x8*)g;
#endif
}

#define VMW3  asm volatile("s_waitcnt vmcnt(3)" ::: "memory")
#define VMW0  asm volatile("s_waitcnt vmcnt(0)" ::: "memory")
#define LGKM0 asm volatile("s_waitcnt lgkmcnt(0)" ::: "memory")

// ---------------------------------------------------------------------------
// Elementwise f32 -> bf16 convert, 8 elems/thread (single buffer: vp)
// ---------------------------------------------------------------------------
__global__ void cvt_f32_bf16(const float* __restrict__ in, bf16* __restrict__ out, int n)
{
    int i = (blockIdx.x * 256 + threadIdx.x) * 8;
    if (i < n) {
        float4 v0 = *(const float4*)(in + i);
        float4 v1 = *(const float4*)(in + i + 4);
        bf16x8 h;
        h[0] = (bf16)v0.x; h[1] = (bf16)v0.y; h[2] = (bf16)v0.z; h[3] = (bf16)v0.w;
        h[4] = (bf16)v1.x; h[5] = (bf16)v1.y; h[6] = (bf16)v1.z; h[7] = (bf16)v1.w;
        *(bf16x8*)(out + i) = h;
    }
}

// 4 weight buffers in one dispatch (grid.y selects; uniform branch)
__global__ void cvt_w4(const float* __restrict__ W0, const float* __restrict__ W1,
                       const float* __restrict__ W2, const float* __restrict__ W3,
                       bf16* __restrict__ o0, bf16* __restrict__ o1,
                       bf16* __restrict__ o2, bf16* __restrict__ o3, int n)
{
    const int s = blockIdx.y;
    const float* in = (s == 0) ? W0 : (s == 1) ? W1 : (s == 2) ? W2 : W3;
    bf16* out = (s == 0) ? o0 : (s == 1) ? o1 : (s == 2) ? o2 : o3;
    int i = (blockIdx.x * 256 + threadIdx.x) * 8;
    if (i < n) {
        float4 v0 = *(const float4*)(in + i);
        float4 v1 = *(const float4*)(in + i + 4);
        bf16x8 h;
        h[0] = (bf16)v0.x; h[1] = (bf16)v0.y; h[2] = (bf16)v0.z; h[3] = (bf16)v0.w;
        h[4] = (bf16)v1.x; h[5] = (bf16)v1.y; h[6] = (bf16)v1.z; h[7] = (bf16)v1.w;
        *(bf16x8*)(out + i) = h;
    }
}

// 3 activation buffers in one dispatch (grid.y selects)
__global__ void cvt_a3(const float* __restrict__ A0, const float* __restrict__ A1,
                       const float* __restrict__ A2,
                       bf16* __restrict__ o0, bf16* __restrict__ o1,
                       bf16* __restrict__ o2, int n)
{
    const int s = blockIdx.y;
    const float* in = (s == 0) ? A0 : (s == 1) ? A1 : A2;
    bf16* out = (s == 0) ? o0 : (s == 1) ? o1 : o2;
    int i = (blockIdx.x * 256 + threadIdx.x) * 8;
    if (i < n) {
        float4 v0 = *(const float4*)(in + i);
        float4 v1 = *(const float4*)(in + i + 4);
        bf16x8 h;
        h[0] = (bf16)v0.x; h[1] = (bf16)v0.y; h[2] = (bf16)v0.z; h[3] = (bf16)v0.w;
        h[4] = (bf16)v1.x; h[5] = (bf16)v1.y; h[6] = (bf16)v1.z; h[7] = (bf16)v1.w;
        *(bf16x8*)(out + i) = h;
    }
}

// ---------------------------------------------------------------------------
// Tiled transpose + convert (used for kp f32 [DK,R] -> kpT bf16 [R,DK])
// ---------------------------------------------------------------------------
__global__ void transpose_cvt(const float* __restrict__ in, bf16* __restrict__ out,
                              int rows, int cols)
{
    __shared__ float t[64][65];
    const float* I = in + (size_t)blockIdx.z * rows * cols;
    bf16* O = out + (size_t)blockIdx.z * rows * cols;
    int c0 = blockIdx.x * 64, r0 = blockIdx.y * 64;
    int tx = threadIdx.x, ty = threadIdx.y;
#pragma unroll
    for (int i = ty; i < 64; i += 4)
        t[i][tx] = I[(size_t)(r0 + i) * cols + c0 + tx];
    __syncthreads();
#pragma unroll
    for (int i = ty; i < 64; i += 4)
        O[(size_t)(c0 + i) * rows + r0 + tx] = (bf16)t[tx][i];
}

// ---------------------------------------------------------------------------
// Grouped QKV GEMM: one dispatch, 3 members {q,k,v}, r8 body per member.
// C[M,N](bf16) = (A[M,K] * W[N,K]^T + bias) * oscale, K==1024.
// 256x128 tile, BK=32, 8 waves, 48KB LDS, counted VMW3, 2-way-free swizzle.
// ---------------------------------------------------------------------------
__global__ __launch_bounds__(512, 4) void gemm_qkv3(
    const bf16* __restrict__ A0, const bf16* __restrict__ A1, const bf16* __restrict__ A2,
    const bf16* __restrict__ W0, const bf16* __restrict__ W1, const bf16* __restrict__ W2,
    const float* __restrict__ b0, const float* __restrict__ b1, const float* __restrict__ b2,
    bf16* __restrict__ C0, bf16* __restrict__ C1, bf16* __restrict__ C2,
    int M, int N, int K, float os0)
{
    __shared__ bf16 As[2][256][32];
    __shared__ bf16 Bs[2][128][32];
    const int tid = threadIdx.x, wv = tid >> 6, lane = tid & 63;
    const int g = lane >> 4, lr = lane & 15;

    const int nwg = gridDim.x;
    const int cpx = nwg >> 3;                      // nwg % 8 == 0 (bijective)
    const int bid = blockIdx.x;
    const int swz = (bid & 7) * cpx + (bid >> 3);
    const int gx = N >> 7;
    const int mt = swz / gx, nt = swz % gx;
    const int m0 = mt * 256, n0 = nt * 128;
    const int wm = (wv >> 1) * 64, wn = (wv & 1) * 64;

    const int srow = lane >> 2;
    const int scol = ((lane & 3) ^ ((lane >> 4) & 3)) * 8;

    const bf16* Acur;
    const bf16* Wcur;

    auto stageA = [&](int buf, int tk) {
#pragma unroll
        for (int s2 = 0; s2 < 2; ++s2) {
            int c = wv * 2 + s2;
            gl2lds16(Acur + (size_t)(m0 + c * 16 + srow) * 1024 + tk * 32 + scol,
                     &As[buf][c * 16][0], lane);
        }
    };
    auto stageB = [&](int buf, int tk) {
        gl2lds16(Wcur + (size_t)(n0 + wv * 16 + srow) * 1024 + tk * 32 + scol,
                 &Bs[buf][wv * 16][0], lane);
    };

#define PHK(PB, STAGE_STMT, VM_STMT)                                             \
    {                                                                            \
        const int so = (g ^ (lr >> 2)) << 4;                                     \
        bf16x8 aF[4], bF[4];                                                     \
        _Pragma("unroll") for (int mm = 0; mm < 4; ++mm)                         \
            aF[mm] = *(const bf16x8*)((const char*)&As[PB][wm + mm * 16 + lr][0] + so); \
        _Pragma("unroll") for (int nn = 0; nn < 4; ++nn)                         \
            bF[nn] = *(const bf16x8*)((const char*)&Bs[PB][wn + nn * 16 + lr][0] + so); \
        LGKM0;                                                                   \
        __builtin_amdgcn_s_barrier();              /* all waves' reads done */   \
        STAGE_STMT;                                /* overwrite buffer PB */     \
        VM_STMT;                                   /* drain tile t+1 */          \
        __builtin_amdgcn_s_barrier();              /* next buffer visible */     \
        __builtin_amdgcn_sched_barrier(0);                                       \
        __builtin_amdgcn_s_setprio(1);                                           \
        _Pragma("unroll") for (int mm = 0; mm < 4; ++mm) {                       \
            _Pragma("unroll") for (int nn = 0; nn < 4; ++nn) {                   \
                acc[mm][nn] = __builtin_amdgcn_mfma_f32_16x16x32_bf16(           \
                    aF[mm], bF[nn], acc[mm][nn], 0, 0, 0); } }                   \
        __builtin_amdgcn_s_setprio(0);                                           \
    }

#pragma unroll 1
    for (int mem = 0; mem < 3; ++mem) {
        Acur = (mem == 0) ? A0 : (mem == 1) ? A1 : A2;
        Wcur = (mem == 0) ? W0 : (mem == 1) ? W1 : W2;
        const float* bias = (mem == 0) ? b0 : (mem == 1) ? b1 : b2;
        bf16* Cp = (mem == 0) ? C0 : (mem == 1) ? C1 : C2;
        const float oscale = (mem == 0) ? os0 : 1.0f;

        f32x4 acc[4][4] = {};

        // prologue: stage tiles 0,1 (6 loads); VMW3 drains tile 0
        stageA(0, 0); stageB(0, 0);
        stageA(1, 1); stageB(1, 1);
        VMW3;
        __builtin_amdgcn_s_barrier();

#pragma unroll 1
        for (int t = 0; t < 30; ++t) {
            const int pb = t & 1;
            PHK(pb, { stageA(pb, t + 2); stageB(pb, t + 2); }, VMW3);
        }
        PHK(0, (void)0, VMW0);
        PHK(1, (void)0, (void)0);

        float bv[4];
#pragma unroll
        for (int n = 0; n < 4; ++n) bv[n] = bias[n0 + wn + n * 16 + lr];

        // bounce through LDS (swizzled, 4KB/wave) -> 16B coalesced stores
        char* myb = (char*)&As[0][0][0] + wv * 4096;
#pragma unroll
        for (int mh = 0; mh < 2; ++mh) {
#pragma unroll
            for (int mm = 0; mm < 2; ++mm)
#pragma unroll
                for (int n = 0; n < 4; ++n) {
                    int colb = (n * 16 + lr) * 2;
#pragma unroll
                    for (int i = 0; i < 4; ++i) {
                        int row = mm * 16 + 4 * g + i;
                        *(bf16*)(myb + row * 128 + (colb ^ ((row & 7) << 4))) =
                            (bf16)((acc[mh * 2 + mm][n][i] + bv[n]) * oscale);
                    }
                }
            __builtin_amdgcn_wave_barrier();
            bf16* Cb = Cp + (size_t)(m0 + wm + mh * 32) * N + n0 + wn;
#pragma unroll
            for (int it = 0; it < 4; ++it) {
                int r = it * 8 + (lane >> 3);
                int sl = lane & 7;
                bf16x8 vv = *(const bf16x8*)(myb + r * 128 + ((sl ^ (r & 7)) << 4));
                *(bf16x8*)(Cb + (size_t)r * N + sl * 8) = vv;
            }
            __builtin_amdgcn_wave_barrier();
        }
        __syncthreads();    // LDS (bounce area) free before next member stages
    }
#undef PHK
}

// ---------------------------------------------------------------------------
// gemm_bt (r8 structure, frozen): bf16 A, f32 out — Wo projection only.
// ---------------------------------------------------------------------------
__global__ __launch_bounds__(512, 4) void gemm_bt(const bf16* __restrict__ A,
                                                  const bf16* __restrict__ W,
                                                  const float* __restrict__ bias,
                                                  float* __restrict__ Cp,
                                                  int M, int N, int K, float oscale)
{
    __shared__ bf16 As[2][256][32];
    __shared__ bf16 Bs[2][128][32];
    const int tid = threadIdx.x, wv = tid >> 6, lane = tid & 63;
    const int g = lane >> 4, lr = lane & 15;

    const int nwg = gridDim.x;
    const int cpx = nwg >> 3;
    const int bid = blockIdx.x;
    const int swz = (bid & 7) * cpx + (bid >> 3);
    const int gx = N >> 7;
    const int mt = swz / gx, nt = swz % gx;
    const int m0 = mt * 256, n0 = nt * 128;
    const int wm = (wv >> 1) * 64, wn = (wv & 1) * 64;

    const int srow = lane >> 2;
    const int scol = ((lane & 3) ^ ((lane >> 4) & 3)) * 8;

    f32x4 acc[4][4] = {};

    auto stageA = [&](int buf, int tk) {
#pragma unroll
        for (int s2 = 0; s2 < 2; ++s2) {
            int c = wv * 2 + s2;
            gl2lds16(A + (size_t)(m0 + c * 16 + srow) * 1024 + tk * 32 + scol,
                     &As[buf][c * 16][0], lane);
        }
    };
    auto stageB = [&](int buf, int tk) {
        gl2lds16(W + (size_t)(n0 + wv * 16 + srow) * 1024 + tk * 32 + scol,
                 &Bs[buf][wv * 16][0], lane);
    };

#define PHK(PB, STAGE_STMT, VM_STMT)                                             \
    {                                                                            \
        const int so = (g ^ (lr >> 2)) << 4;                                     \
        bf16x8 aF[4], bF[4];                                                     \
        _Pragma("unroll") for (int mm = 0; mm < 4; ++mm)                         \
            aF[mm] = *(const bf16x8*)((const char*)&As[PB][wm + mm * 16 + lr][0] + so); \
        _Pragma("unroll") for (int nn = 0; nn < 4; ++nn)                         \
            bF[nn] = *(const bf16x8*)((const char*)&Bs[PB][wn + nn * 16 + lr][0] + so); \
        LGKM0;                                                                   \
        __builtin_amdgcn_s_barrier();                                            \
        STAGE_STMT;                                                              \
        VM_STMT;                                                                 \
        __builtin_amdgcn_s_barrier();                                            \
        __builtin_amdgcn_sched_barrier(0);                                       \
        __builtin_amdgcn_s_setprio(1);                                           \
        _Pragma("unroll") for (int mm = 0; mm < 4; ++mm) {                       \
            _Pragma("unroll") for (int nn = 0; nn < 4; ++nn) {                   \
                acc[mm][nn] = __builtin_amdgcn_mfma_f32_16x16x32_bf16(           \
                    aF[mm], bF[nn], acc[mm][nn], 0, 0, 0); } }                   \
        __builtin_amdgcn_s_setprio(0);                                           \
    }

    stageA(0, 0); stageB(0, 0);
    stageA(1, 1); stageB(1, 1);
    VMW3;
    __builtin_amdgcn_s_barrier();

#pragma unroll 1
    for (int t = 0; t < 30; ++t) {
        const int pb = t & 1;
        PHK(pb, { stageA(pb, t + 2); stageB(pb, t + 2); }, VMW3);
    }
    PHK(0, (void)0, VMW0);
    PHK(1, (void)0, (void)0);
#undef PHK

    float bv[4];
#pragma unroll
    for (int n = 0; n < 4; ++n) bv[n] = bias[n0 + wn + n * 16 + lr];

#pragma unroll
    for (int n = 0; n < 4; ++n) {
        int col = n0 + wn + n * 16 + lr;
#pragma unroll
        for (int m = 0; m < 4; ++m) {
            int row = m0 + wm + m * 16 + 4 * g;
#pragma unroll
            for (int i = 0; i < 4; ++i)
                Cp[(size_t)(row + i) * N + col] = (acc[m][n][i] + bv[n]) * oscale;
        }
    }
}

// ---------------------------------------------------------------------------
// kpvp pair in one dispatch: blockIdx.z = b*2 + sel (sel 0: k/E, 1: v/F).
// kp[b,h,d,r] += sum_{s in chunk} X[b,s,h*64+d] * E[h,s,r]
// E/F read DIRECTLY as f32 [H,S,R] (fused transpose+convert in registers).
// ---------------------------------------------------------------------------
__global__ __launch_bounds__(256) void kpvp_gemm2(const bf16* __restrict__ K_,
                                                  const float* __restrict__ Ea,
                                                  float* __restrict__ ko,
                                                  const bf16* __restrict__ V_,
                                                  const float* __restrict__ Fa,
                                                  float* __restrict__ vo)
{
    __shared__ bf16 Ak[64][40];
    const int zz = blockIdx.z, b = zz >> 1, sel = zz & 1;
    const bf16* X = sel ? V_ : K_;
    const float* E = sel ? Fa : Ea;
    float* out = sel ? vo : ko;
    const int h = blockIdx.y;
    const int s0 = blockIdx.x * 512;
    const int tid = threadIdx.x, wv = tid >> 6, lane = tid & 63;
    const int g = lane >> 4, lr = lane & 15;
    const float* Eh = E + (size_t)h * SS * RR;
    const int rbase = wv * 64 + lr;
    f32x4 acc[4][4] = {};

    for (int kt = 0; kt < 512; kt += 32) {
        const int sb = s0 + kt;
        __syncthreads();
        float ef[4][8];
        const float* Eb = Eh + (size_t)(sb + g * 8) * RR + rbase;
#pragma unroll
        for (int n = 0; n < 4; ++n)
#pragma unroll
            for (int j = 0; j < 8; ++j)
                ef[n][j] = Eb[(size_t)j * RR + n * 16];
        {   // A-stage with transpose: X[b, sb+sl, h*64+dblk+j] -> Ak[dblk+j][sl]
            int sl = tid >> 3, dblk = (tid & 7) * 8;
            bf16x8 v = *(const bf16x8*)(X + ((size_t)b * SS + sb + sl) * DD + h * DK + dblk);
#pragma unroll
            for (int j = 0; j < 8; ++j) Ak[dblk + j][sl] = v[j];
        }
        bf16x8 bb[4];
#pragma unroll
        for (int n = 0; n < 4; ++n)
#pragma unroll
            for (int j = 0; j < 8; ++j)
                bb[n][j] = (bf16)ef[n][j];
        __syncthreads();

        bf16x8 a[4];
#pragma unroll
        for (int m = 0; m < 4; ++m) a[m] = *(const bf16x8*)&Ak[m * 16 + lr][g * 8];
#pragma unroll
        for (int m = 0; m < 4; ++m)
#pragma unroll
            for (int n = 0; n < 4; ++n)
                acc[m][n] = __builtin_amdgcn_mfma_f32_16x16x32_bf16(a[m], bb[n], acc[m][n], 0, 0, 0);
    }

    float* o = out + ((size_t)(b * HH + h)) * DK * RR;
#pragma unroll
    for (int m = 0; m < 4; ++m)
#pragma unroll
        for (int n = 0; n < 4; ++n) {
            int r = wv * 64 + n * 16 + lr;
#pragma unroll
            for (int i = 0; i < 4; ++i)
                atomicAdd(o + (size_t)(m * 16 + 4 * g + i) * RR + r, acc[m][n][i]);
        }
}

// ---------------------------------------------------------------------------
// Fused attention (r8 structure, frozen at 57us): 256 blocks x 8 waves,
// single accumulator, KP/VP staged once, barrier-free inner loop, exp2
// softmax, deferred norm, LDS-bounced coalesced ctx stores.
// ---------------------------------------------------------------------------
__global__ __launch_bounds__(512) void attn_fused(const bf16* __restrict__ qb,
                                                  const bf16* __restrict__ kpt,
                                                  const bf16* __restrict__ vpb,
                                                  bf16* __restrict__ ctx)
{
    __shared__ bf16 KPs[256][72];      // kpT tile [r][d]
    __shared__ bf16 VPs[64][264];      // vp tile [d][r]
    __shared__ bf16 Ps[8][16][264];    // per-wave P / out-bounce tile
    const int b = blockIdx.z, h = blockIdx.y, qt = blockIdx.x;
    const int tid = threadIdx.x, wv = tid >> 6, lane = tid & 63;
    const int g = lane >> 4, lr = lane & 15;
    const bf16* kph = kpt + ((size_t)(b * HH + h)) * RR * DK;
    const bf16* vph = vpb + ((size_t)(b * HH + h)) * DK * RR;

#pragma unroll
    for (int p = 0; p < 4; ++p) {
        int f = p * 512 + tid;
        *(bf16x8*)&KPs[f >> 3][(f & 7) * 8] = *(const bf16x8*)(kph + (size_t)f * 8);
        *(bf16x8*)&VPs[f >> 5][(f & 31) * 8] = *(const bf16x8*)(vph + (size_t)f * 8);
    }

    const bf16* qbase = qb + (size_t)b * SS * DD + h * DK;
    int row0 = qt * 1024 + wv * 16;
    bf16x8 aq0 = *(const bf16x8*)(qbase + (size_t)(row0 + lr) * DD + g * 8);
    bf16x8 aq1 = *(const bf16x8*)(qbase + (size_t)(row0 + lr) * DD + 32 + g * 8);
    __syncthreads();

    for (int it = 0; it < 8; ++it) {
        f32x4 acc[16] = {};
        __builtin_amdgcn_s_setprio(1);
#pragma unroll
        for (int nf = 0; nf < 16; ++nf) {
            bf16x8 b0 = *(const bf16x8*)&KPs[nf * 16 + lr][g * 8];
            bf16x8 b1 = *(const bf16x8*)&KPs[nf * 16 + lr][32 + g * 8];
            acc[nf] = __builtin_amdgcn_mfma_f32_16x16x32_bf16(aq0, b0, acc[nf], 0, 0, 0);
            acc[nf] = __builtin_amdgcn_mfma_f32_16x16x32_bf16(aq1, b1, acc[nf], 0, 0, 0);
        }
        __builtin_amdgcn_s_setprio(0);

        bf16x8 aqn0 = aq0, aqn1 = aq1;
        if (it < 7) {
            const bf16* qr = qbase + (size_t)(row0 + 128 + lr) * DD;
            aqn0 = *(const bf16x8*)(qr + g * 8);
            aqn1 = *(const bf16x8*)(qr + 32 + g * 8);
        }

        float rs[4];
#pragma unroll
        for (int i = 0; i < 4; ++i) {
            float s = 0.f;
#pragma unroll
            for (int nf = 0; nf < 16; ++nf) {
                float pv = exp2f(acc[nf][i]);
                acc[nf][i] = pv;
                s += pv;
            }
#pragma unroll
            for (int msk = 1; msk < 16; msk <<= 1) s += __shfl_xor(s, msk, 64);
            rs[i] = 1.f / s;
        }

#pragma unroll
        for (int nf = 0; nf < 16; ++nf)
#pragma unroll
            for (int i = 0; i < 4; ++i)
                Ps[wv][4 * g + i][nf * 16 + lr] = (bf16)acc[nf][i];
        __builtin_amdgcn_wave_barrier();

        f32x4 o[4] = {};
        __builtin_amdgcn_s_setprio(1);
#pragma unroll
        for (int ks = 0; ks < 8; ++ks) {
            bf16x8 pa = *(const bf16x8*)&Ps[wv][lr][ks * 32 + g * 8];
#pragma unroll
            for (int n = 0; n < 4; ++n) {
                bf16x8 vb = *(const bf16x8*)&VPs[n * 16 + lr][ks * 32 + g * 8];
                o[n] = __builtin_amdgcn_mfma_f32_16x16x32_bf16(pa, vb, o[n], 0, 0, 0);
            }
        }
        __builtin_amdgcn_s_setprio(0);
        __builtin_amdgcn_wave_barrier();

#pragma unroll
        for (int n = 0; n < 4; ++n)
#pragma unroll
            for (int i = 0; i < 4; ++i)
                Ps[wv][4 * g + i][n * 16 + lr] = (bf16)(o[n][i] * rs[i]);
        __builtin_amdgcn_wave_barrier();
        bf16* crow = ctx + (size_t)(b * SS + row0) * DD + h * DK;
#pragma unroll
        for (int p = 0; p < 2; ++p) {
            int r = p * 8 + (lane >> 3), c = (lane & 7) * 8;
            bf16x8 ov = *(const bf16x8*)&Ps[wv][r][c];
            *(bf16x8*)(crow + (size_t)r * DD + c) = ov;
        }
        __builtin_amdgcn_wave_barrier();

        aq0 = aqn0; aq1 = aqn1;
        row0 += 128;
    }
}

// ---------------------------------------------------------------------------
extern "C" void kernel_launch(void* const* d_in, const int* in_sizes, int n_in,
                              void* d_out, int out_size, void* d_ws, size_t ws_size,
                              hipStream_t stream)
{
    const float* query = (const float*)d_in[0];
    const float* key   = (const float*)d_in[1];
    const float* value = (const float*)d_in[2];
    const float* Wq = (const float*)d_in[3];  const float* bq = (const float*)d_in[4];
    const float* Wk = (const float*)d_in[5];  const float* bk = (const float*)d_in[6];
    const float* Wv = (const float*)d_in[7];  const float* bv = (const float*)d_in[8];
    const float* Wo = (const float*)d_in[9];  const float* bo = (const float*)d_in[10];
    const float* E  = (const float*)d_in[11];
    const float* F  = (const float*)d_in[12];

    char* w = (char*)d_ws;
    size_t off = 0;
    auto alloc = [&](size_t bytes) -> char* {
        char* p = w + off;
        off += (bytes + 255) & ~(size_t)255;
        return p;
    };

    const size_t DW   = (size_t)DD * DD;           // 1M
    const size_t BSD  = (size_t)BB * SS * DD;      // 16.78M
    const size_t BHDR = (size_t)BB * HH * DK * RR; // 4.19M

    bf16* wqb = (bf16*)alloc(DW * 2);
    bf16* wkb = (bf16*)alloc(DW * 2);
    bf16* wvb = (bf16*)alloc(DW * 2);
    bf16* wob = (bf16*)alloc(DW * 2);
    bf16* qin = (bf16*)alloc(BSD * 2);             // bf16 inputs; later reused:
    bf16* kin = (bf16*)alloc(BSD * 2);             //   qin -> kpf/vpf, kin -> kpt/vp,
    bf16* vin = (bf16*)alloc(BSD * 2);             //   vin -> ctx
    bf16* qbuf = (bf16*)alloc(BSD * 2);
    bf16* kbuf = (bf16*)alloc(BSD * 2);
    bf16* vbuf = (bf16*)alloc(BSD * 2);
    if (off > ws_size) return;

    // aliased scratch (stream-ordered reuse; regions dead by first write)
    float* kpf  = (float*)qin;                     // BHDR f32
    float* vpf  = kpf + BHDR;                      // BHDR f32
    bf16*  kpt  = (bf16*)kin;                      // BHDR bf16 [B,H,R,DK]
    bf16*  vpbb = kpt + BHDR;                      // BHDR bf16 [B,H,DK,R]
    bf16*  ctx  = (bf16*)vin;                      // BSD bf16

    // 1. converts: 4 weights in one dispatch, 3 activations in one dispatch
    cvt_w4<<<dim3((int)(DW / 2048), 4), 256, 0, stream>>>(
        Wq, Wk, Wv, Wo, wqb, wkb, wvb, wob, (int)DW);
    cvt_a3<<<dim3((int)(BSD / 2048), 3), 256, 0, stream>>>(
        query, key, value, qin, kin, vin, (int)BSD);

    // 2. QKV projections: grouped into one dispatch (r8 body x 3 members)
    const int nwg = ((BB * SS) / 256) * (DD / 128);   // 512, % 8 == 0
    gemm_qkv3<<<nwg, 512, 0, stream>>>(qin, kin, vin, wqb, wkb, wvb,
                                       bq, bk, bv, qbuf, kbuf, vbuf,
                                       BB * SS, DD, DD, QSCALE);

    // 3. kp/vp = k^T E, v^T F — one dispatch (grid.z parity selects pair)
    hipMemsetAsync(kpf, 0, BHDR * 4 * 2, stream);
    kpvp_gemm2<<<dim3(SS / 512, HH, BB * 2), 256, 0, stream>>>(
        kbuf, E, kpf, vbuf, F, vpf);

    // 4. kp -> kpT bf16 [B,H,R,DK]; vp -> bf16 [B,H,DK,R]  (kin region dead)
    dim3 tb(64, 4);
    transpose_cvt<<<dim3(RR / 64, DK / 64, BB * HH), tb, 0, stream>>>(kpf, kpt, DK, RR);
    cvt_f32_bf16<<<(int)(BHDR / 2048), 256, 0, stream>>>(vpf, vpbb, (int)BHDR);

    // 5. fused softmax attention (vin region dead -> ctx)
    attn_fused<<<dim3(SS / 1024, HH, BB), 512, 0, stream>>>(qbuf, kpt, vpbb, ctx);

    // 6. output projection -> f32 d_out
    gemm_bt<<<nwg, 512, 0, stream>>>(ctx, wob, bo, (float*)d_out, BB * SS, DD, DD, 1.0f);
}

// Round 17
// 383.762 us; speedup vs baseline: 1.1078x; 1.1078x over previous
//
#include <hip/hip_runtime.h>

// ---------------------------------------------------------------------------
// LinearAttention (Linformer-style) on MI355X, bf16 MFMA pipeline, f32 accum.
// B=4 S=4096 D=1024 H=16 R=256 DK=64
// Round 17: FINAL revert to the r10/r15 state (384.4 us, reproduced twice).
//   r16's grouped-QKV dispatch spilled (loop-variant member pointers captured
//   by reference -> acc demoted; VGPR 64, +90MB scratch) and regressed to
//   425 us. Seven consecutive deviations from this structure (r11-r16) have
//   regressed or nulled; this configuration is the converged optimum of the
//   explored design family:
//   - gemm_bt: 256x128 tile, BK=32, 8 waves, 48KB LDS, launch_bounds(512,4)
//     -> 2-3 co-resident blocks/CU; counted VMW3 (prefetch distance 1 tile);
//     2-way-free XOR swizzle both-sides; swizzled-LDS-bounce bf16 C-stores.
//   - attn_fused: 256 blocks x 8 waves, KP/VP staged once per 1024 rows,
//     single accumulator, exp2 softmax (scale folded into q-projection),
//     deferred normalization, wave-private P tiles (1 block barrier total).
//   - kpvp_gemm: E/F read directly as f32 (fused transpose+convert).
//   - separate vectorized f32->bf16 converts (all fusion attempts failed).
// ---------------------------------------------------------------------------

typedef __bf16 bf16;
typedef bf16 bf16x8 __attribute__((ext_vector_type(8)));
typedef bf16 bf16x4 __attribute__((ext_vector_type(4)));
typedef float f32x4 __attribute__((ext_vector_type(4)));

constexpr int BB = 4, SS = 4096, DD = 1024, HH = 16, RR = 256, DK = 64;

// q-projection output pre-scale: logits*log2e/8 so softmax uses exp2 directly
#define QSCALE 0.1803368801111204f

// async global->LDS, 16B per lane. ldsbase must be wave-uniform; HW writes
// lane l's 16B at ldsbase + l*16. gptr is per-lane.
__device__ __forceinline__ void gl2lds16(const void* g, void* l, int lane)
{
#if __has_builtin(__builtin_amdgcn_global_load_lds)
    auto gp = reinterpret_cast<const __attribute__((address_space(1))) void*>(
        reinterpret_cast<uintptr_t>(g));
    auto lp = reinterpret_cast<__attribute__((address_space(3))) void*>(
        reinterpret_cast<uintptr_t>(l));
    __builtin_amdgcn_global_load_lds(gp, lp, 16, 0, 0);
    (void)lane;
#else
    *(bf16x8*)((char*)l + lane * 16) = *(const bf16x8*)g;
#endif
}

#define VMW3  asm volatile("s_waitcnt vmcnt(3)" ::: "memory")
#define VMW0  asm volatile("s_waitcnt vmcnt(0)" ::: "memory")
#define LGKM0 asm volatile("s_waitcnt lgkmcnt(0)" ::: "memory")

// ---------------------------------------------------------------------------
// Elementwise f32 -> bf16 convert, 8 elems/thread
// ---------------------------------------------------------------------------
__global__ void cvt_f32_bf16(const float* __restrict__ in, bf16* __restrict__ out, int n)
{
    int i = (blockIdx.x * 256 + threadIdx.x) * 8;
    if (i < n) {
        float4 v0 = *(const float4*)(in + i);
        float4 v1 = *(const float4*)(in + i + 4);
        bf16x8 h;
        h[0] = (bf16)v0.x; h[1] = (bf16)v0.y; h[2] = (bf16)v0.z; h[3] = (bf16)v0.w;
        h[4] = (bf16)v1.x; h[5] = (bf16)v1.y; h[6] = (bf16)v1.z; h[7] = (bf16)v1.w;
        *(bf16x8*)(out + i) = h;
    }
}

// ---------------------------------------------------------------------------
// Tiled transpose + convert (used for kp f32 [DK,R] -> kpT bf16 [R,DK])
// ---------------------------------------------------------------------------
__global__ void transpose_cvt(const float* __restrict__ in, bf16* __restrict__ out,
                              int rows, int cols)
{
    __shared__ float t[64][65];
    const float* I = in + (size_t)blockIdx.z * rows * cols;
    bf16* O = out + (size_t)blockIdx.z * rows * cols;
    int c0 = blockIdx.x * 64, r0 = blockIdx.y * 64;
    int tx = threadIdx.x, ty = threadIdx.y;
#pragma unroll
    for (int i = ty; i < 64; i += 4)
        t[i][tx] = I[(size_t)(r0 + i) * cols + c0 + tx];
    __syncthreads();
#pragma unroll
    for (int i = ty; i < 64; i += 4)
        O[(size_t)(c0 + i) * rows + r0 + tx] = (bf16)t[tx][i];
}

// ---------------------------------------------------------------------------
// C[M,N] = (A[M,K](bf16) * W[N,K]^T(bf16) + bias[N]) * oscale.   K == 1024.
// Round-8 structure (frozen): 256x128 tile, BK=32, 8 waves (4M x 2N), 48KB LDS
// -> co-resident blocks; counted VMW3; 64B-row swizzle.
// ---------------------------------------------------------------------------
template <bool OUT_F32>
__global__ __launch_bounds__(512, 4) void gemm_bt(const bf16* __restrict__ A,
                                                  const bf16* __restrict__ W,
                                                  const float* __restrict__ bias,
                                                  void* __restrict__ Cp,
                                                  int M, int N, int K, float oscale)
{
    __shared__ bf16 As[2][256][32];
    __shared__ bf16 Bs[2][128][32];
    const int tid = threadIdx.x, wv = tid >> 6, lane = tid & 63;
    const int g = lane >> 4, lr = lane & 15;

    const int nwg = gridDim.x;
    const int cpx = nwg >> 3;                      // nwg % 8 == 0 (bijective)
    const int bid = blockIdx.x;
    const int swz = (bid & 7) * cpx + (bid >> 3);
    const int gx = N >> 7;
    const int mt = swz / gx, nt = swz % gx;
    const int m0 = mt * 256, n0 = nt * 128;
    const int wm = (wv >> 1) * 64, wn = (wv & 1) * 64;

    const int srow = lane >> 2;
    const int scol = ((lane & 3) ^ ((lane >> 4) & 3)) * 8;

    f32x4 acc[4][4] = {};

    auto stageA = [&](int buf, int tk) {
#pragma unroll
        for (int s2 = 0; s2 < 2; ++s2) {
            int c = wv * 2 + s2;
            gl2lds16(A + (size_t)(m0 + c * 16 + srow) * 1024 + tk * 32 + scol,
                     &As[buf][c * 16][0], lane);
        }
    };
    auto stageB = [&](int buf, int tk) {
        gl2lds16(W + (size_t)(n0 + wv * 16 + srow) * 1024 + tk * 32 + scol,
                 &Bs[buf][wv * 16][0], lane);
    };

#define PHK(PB, STAGE_STMT, VM_STMT)                                             \
    {                                                                            \
        const int so = (g ^ (lr >> 2)) << 4;                                     \
        bf16x8 aF[4], bF[4];                                                     \
        _Pragma("unroll") for (int mm = 0; mm < 4; ++mm)                         \
            aF[mm] = *(const bf16x8*)((const char*)&As[PB][wm + mm * 16 + lr][0] + so); \
        _Pragma("unroll") for (int nn = 0; nn < 4; ++nn)                         \
            bF[nn] = *(const bf16x8*)((const char*)&Bs[PB][wn + nn * 16 + lr][0] + so); \
        LGKM0;                                                                   \
        __builtin_amdgcn_s_barrier();              /* all waves' reads done */   \
        STAGE_STMT;                                /* overwrite buffer PB */     \
        VM_STMT;                                   /* drain tile t+1 */          \
        __builtin_amdgcn_s_barrier();              /* next buffer visible */     \
        __builtin_amdgcn_sched_barrier(0);                                       \
        __builtin_amdgcn_s_setprio(1);                                           \
        _Pragma("unroll") for (int mm = 0; mm < 4; ++mm) {                       \
            _Pragma("unroll") for (int nn = 0; nn < 4; ++nn) {                   \
                acc[mm][nn] = __builtin_amdgcn_mfma_f32_16x16x32_bf16(           \
                    aF[mm], bF[nn], acc[mm][nn], 0, 0, 0); } }                   \
        __builtin_amdgcn_s_setprio(0);                                           \
    }

    stageA(0, 0); stageB(0, 0);
    stageA(1, 1); stageB(1, 1);
    VMW3;
    __builtin_amdgcn_s_barrier();

#pragma unroll 1
    for (int t = 0; t < 30; ++t) {
        const int pb = t & 1;
        PHK(pb, { stageA(pb, t + 2); stageB(pb, t + 2); }, VMW3);
    }
    PHK(0, (void)0, VMW0);
    PHK(1, (void)0, (void)0);
#undef PHK

    float bv[4];
#pragma unroll
    for (int n = 0; n < 4; ++n) bv[n] = bias[n0 + wn + n * 16 + lr];

    if constexpr (OUT_F32) {
#pragma unroll
        for (int n = 0; n < 4; ++n) {
            int col = n0 + wn + n * 16 + lr;
#pragma unroll
            for (int m = 0; m < 4; ++m) {
                int row = m0 + wm + m * 16 + 4 * g;
#pragma unroll
                for (int i = 0; i < 4; ++i)
                    ((float*)Cp)[(size_t)(row + i) * N + col] = (acc[m][n][i] + bv[n]) * oscale;
            }
        }
    } else {
        char* myb = (char*)&As[0][0][0] + wv * 4096;
#pragma unroll
        for (int mh = 0; mh < 2; ++mh) {
#pragma unroll
            for (int mm = 0; mm < 2; ++mm)
#pragma unroll
                for (int n = 0; n < 4; ++n) {
                    int colb = (n * 16 + lr) * 2;
#pragma unroll
                    for (int i = 0; i < 4; ++i) {
                        int row = mm * 16 + 4 * g + i;
                        *(bf16*)(myb + row * 128 + (colb ^ ((row & 7) << 4))) =
                            (bf16)((acc[mh * 2 + mm][n][i] + bv[n]) * oscale);
                    }
                }
            __builtin_amdgcn_wave_barrier();
            bf16* Cb = (bf16*)Cp + (size_t)(m0 + wm + mh * 32) * N + n0 + wn;
#pragma unroll
            for (int it = 0; it < 4; ++it) {
                int r = it * 8 + (lane >> 3);
                int sl = lane & 7;
                bf16x8 vv = *(const bf16x8*)(myb + r * 128 + ((sl ^ (r & 7)) << 4));
                *(bf16x8*)(Cb + (size_t)r * N + sl * 8) = vv;
            }
            __builtin_amdgcn_wave_barrier();
        }
    }
}

// ---------------------------------------------------------------------------
// kp[b,h,d,r] += sum_{s in chunk} X[b,s,h*64+d] * E[h,s,r]
// E read DIRECTLY as f32 [H,S,R] (fused transpose+convert in registers).
// ---------------------------------------------------------------------------
__global__ __launch_bounds__(256) void kpvp_gemm(const bf16* __restrict__ X,
                                                 const float* __restrict__ E,
                                                 float* __restrict__ out)
{
    __shared__ bf16 Ak[64][40];
    const int b = blockIdx.z, h = blockIdx.y;
    const int s0 = blockIdx.x * 512;
    const int tid = threadIdx.x, wv = tid >> 6, lane = tid & 63;
    const int g = lane >> 4, lr = lane & 15;
    const float* Eh = E + (size_t)h * SS * RR;
    const int rbase = wv * 64 + lr;
    f32x4 acc[4][4] = {};

    for (int kt = 0; kt < 512; kt += 32) {
        const int sb = s0 + kt;
        __syncthreads();
        float ef[4][8];
        const float* Eb = Eh + (size_t)(sb + g * 8) * RR + rbase;
#pragma unroll
        for (int n = 0; n < 4; ++n)
#pragma unroll
            for (int j = 0; j < 8; ++j)
                ef[n][j] = Eb[(size_t)j * RR + n * 16];
        {   // A-stage with transpose: X[b, sb+sl, h*64+dblk+j] -> Ak[dblk+j][sl]
            int sl = tid >> 3, dblk = (tid & 7) * 8;
            bf16x8 v = *(const bf16x8*)(X + ((size_t)b * SS + sb + sl) * DD + h * DK + dblk);
#pragma unroll
            for (int j = 0; j < 8; ++j) Ak[dblk + j][sl] = v[j];
        }
        bf16x8 bb[4];
#pragma unroll
        for (int n = 0; n < 4; ++n)
#pragma unroll
            for (int j = 0; j < 8; ++j)
                bb[n][j] = (bf16)ef[n][j];
        __syncthreads();

        bf16x8 a[4];
#pragma unroll
        for (int m = 0; m < 4; ++m) a[m] = *(const bf16x8*)&Ak[m * 16 + lr][g * 8];
#pragma unroll
        for (int m = 0; m < 4; ++m)
#pragma unroll
            for (int n = 0; n < 4; ++n)
                acc[m][n] = __builtin_amdgcn_mfma_f32_16x16x32_bf16(a[m], bb[n], acc[m][n], 0, 0, 0);
    }

    float* o = out + ((size_t)(b * HH + h)) * DK * RR;
#pragma unroll
    for (int m = 0; m < 4; ++m)
#pragma unroll
        for (int n = 0; n < 4; ++n) {
            int r = wv * 64 + n * 16 + lr;
#pragma unroll
            for (int i = 0; i < 4; ++i)
                atomicAdd(o + (size_t)(m * 16 + 4 * g + i) * RR + r, acc[m][n][i]);
        }
}

// ---------------------------------------------------------------------------
// Fused attention (round-8 structure, measured 57us): 256 blocks x 8 waves,
// single accumulator, KP/VP staged once, barrier-free inner loop, exp2
// softmax, deferred norm, LDS-bounced coalesced ctx stores.
// ---------------------------------------------------------------------------
__global__ __launch_bounds__(512) void attn_fused(const bf16* __restrict__ qb,
                                                  const bf16* __restrict__ kpt,
                                                  const bf16* __restrict__ vpb,
                                                  bf16* __restrict__ ctx)
{
    __shared__ bf16 KPs[256][72];      // kpT tile [r][d]
    __shared__ bf16 VPs[64][264];      // vp tile [d][r]
    __shared__ bf16 Ps[8][16][264];    // per-wave P / out-bounce tile
    const int b = blockIdx.z, h = blockIdx.y, qt = blockIdx.x;
    const int tid = threadIdx.x, wv = tid >> 6, lane = tid & 63;
    const int g = lane >> 4, lr = lane & 15;
    const bf16* kph = kpt + ((size_t)(b * HH + h)) * RR * DK;
    const bf16* vph = vpb + ((size_t)(b * HH + h)) * DK * RR;

#pragma unroll
    for (int p = 0; p < 4; ++p) {
        int f = p * 512 + tid;
        *(bf16x8*)&KPs[f >> 3][(f & 7) * 8] = *(const bf16x8*)(kph + (size_t)f * 8);
        *(bf16x8*)&VPs[f >> 5][(f & 31) * 8] = *(const bf16x8*)(vph + (size_t)f * 8);
    }

    const bf16* qbase = qb + (size_t)b * SS * DD + h * DK;
    int row0 = qt * 1024 + wv * 16;
    bf16x8 aq0 = *(const bf16x8*)(qbase + (size_t)(row0 + lr) * DD + g * 8);
    bf16x8 aq1 = *(const bf16x8*)(qbase + (size_t)(row0 + lr) * DD + 32 + g * 8);
    __syncthreads();

    for (int it = 0; it < 8; ++it) {
        f32x4 acc[16] = {};
        __builtin_amdgcn_s_setprio(1);
#pragma unroll
        for (int nf = 0; nf < 16; ++nf) {
            bf16x8 b0 = *(const bf16x8*)&KPs[nf * 16 + lr][g * 8];
            bf16x8 b1 = *(const bf16x8*)&KPs[nf * 16 + lr][32 + g * 8];
            acc[nf] = __builtin_amdgcn_mfma_f32_16x16x32_bf16(aq0, b0, acc[nf], 0, 0, 0);
            acc[nf] = __builtin_amdgcn_mfma_f32_16x16x32_bf16(aq1, b1, acc[nf], 0, 0, 0);
        }
        __builtin_amdgcn_s_setprio(0);

        bf16x8 aqn0 = aq0, aqn1 = aq1;
        if (it < 7) {
            const bf16* qr = qbase + (size_t)(row0 + 128 + lr) * DD;
            aqn0 = *(const bf16x8*)(qr + g * 8);
            aqn1 = *(const bf16x8*)(qr + 32 + g * 8);
        }

        float rs[4];
#pragma unroll
        for (int i = 0; i < 4; ++i) {
            float s = 0.f;
#pragma unroll
            for (int nf = 0; nf < 16; ++nf) {
                float pv = exp2f(acc[nf][i]);
                acc[nf][i] = pv;
                s += pv;
            }
#pragma unroll
            for (int msk = 1; msk < 16; msk <<= 1) s += __shfl_xor(s, msk, 64);
            rs[i] = 1.f / s;
        }

#pragma unroll
        for (int nf = 0; nf < 16; ++nf)
#pragma unroll
            for (int i = 0; i < 4; ++i)
                Ps[wv][4 * g + i][nf * 16 + lr] = (bf16)acc[nf][i];
        __builtin_amdgcn_wave_barrier();

        f32x4 o[4] = {};
        __builtin_amdgcn_s_setprio(1);
#pragma unroll
        for (int ks = 0; ks < 8; ++ks) {
            bf16x8 pa = *(const bf16x8*)&Ps[wv][lr][ks * 32 + g * 8];
#pragma unroll
            for (int n = 0; n < 4; ++n) {
                bf16x8 vb = *(const bf16x8*)&VPs[n * 16 + lr][ks * 32 + g * 8];
                o[n] = __builtin_amdgcn_mfma_f32_16x16x32_bf16(pa, vb, o[n], 0, 0, 0);
            }
        }
        __builtin_amdgcn_s_setprio(0);
        __builtin_amdgcn_wave_barrier();

#pragma unroll
        for (int n = 0; n < 4; ++n)
#pragma unroll
            for (int i = 0; i < 4; ++i)
                Ps[wv][4 * g + i][n * 16 + lr] = (bf16)(o[n][i] * rs[i]);
        __builtin_amdgcn_wave_barrier();
        bf16* crow = ctx + (size_t)(b * SS + row0) * DD + h * DK;
#pragma unroll
        for (int p = 0; p < 2; ++p) {
            int r = p * 8 + (lane >> 3), c = (lane & 7) * 8;
            bf16x8 ov = *(const bf16x8*)&Ps[wv][r][c];
            *(bf16x8*)(crow + (size_t)r * DD + c) = ov;
        }
        __builtin_amdgcn_wave_barrier();

        aq0 = aqn0; aq1 = aqn1;
        row0 += 128;
    }
}

// ---------------------------------------------------------------------------
extern "C" void kernel_launch(void* const* d_in, const int* in_sizes, int n_in,
                              void* d_out, int out_size, void* d_ws, size_t ws_size,
                              hipStream_t stream)
{
    const float* query = (const float*)d_in[0];
    const float* key   = (const float*)d_in[1];
    const float* value = (const float*)d_in[2];
    const float* Wq = (const float*)d_in[3];  const float* bq = (const float*)d_in[4];
    const float* Wk = (const float*)d_in[5];  const float* bk = (const float*)d_in[6];
    const float* Wv = (const float*)d_in[7];  const float* bv = (const float*)d_in[8];
    const float* Wo = (const float*)d_in[9];  const float* bo = (const float*)d_in[10];
    const float* E  = (const float*)d_in[11];
    const float* F  = (const float*)d_in[12];

    char* w = (char*)d_ws;
    size_t off = 0;
    auto alloc = [&](size_t bytes) -> char* {
        char* p = w + off;
        off += (bytes + 255) & ~(size_t)255;
        return p;
    };

    const size_t DW   = (size_t)DD * DD;           // 1M
    const size_t BSD  = (size_t)BB * SS * DD;      // 16.78M
    const size_t BHDR = (size_t)BB * HH * DK * RR; // 4.19M

    bf16* wqb = (bf16*)alloc(DW * 2);
    bf16* wkb = (bf16*)alloc(DW * 2);
    bf16* wvb = (bf16*)alloc(DW * 2);
    bf16* wob = (bf16*)alloc(DW * 2);
    bf16* qin = (bf16*)alloc(BSD * 2);             // bf16 inputs; later reused:
    bf16* kin = (bf16*)alloc(BSD * 2);             //   qin -> kpf/vpf, kin -> kpt/vp,
    bf16* vin = (bf16*)alloc(BSD * 2);             //   vin -> ctx
    bf16* qbuf = (bf16*)alloc(BSD * 2);
    bf16* kbuf = (bf16*)alloc(BSD * 2);
    bf16* vbuf = (bf16*)alloc(BSD * 2);
    if (off > ws_size) return;

    // aliased scratch (stream-ordered reuse; regions dead by first write)
    float* kpf  = (float*)qin;                     // BHDR f32
    float* vpf  = kpf + BHDR;                      // BHDR f32
    bf16*  kpt  = (bf16*)kin;                      // BHDR bf16 [B,H,R,DK]
    bf16*  vpbb = kpt + BHDR;                      // BHDR bf16 [B,H,DK,R]
    bf16*  ctx  = (bf16*)vin;                      // BSD bf16

    // 1. converts: weights + activations
    cvt_f32_bf16<<<(int)(DW / 2048), 256, 0, stream>>>(Wq, wqb, (int)DW);
    cvt_f32_bf16<<<(int)(DW / 2048), 256, 0, stream>>>(Wk, wkb, (int)DW);
    cvt_f32_bf16<<<(int)(DW / 2048), 256, 0, stream>>>(Wv, wvb, (int)DW);
    cvt_f32_bf16<<<(int)(DW / 2048), 256, 0, stream>>>(Wo, wob, (int)DW);
    cvt_f32_bf16<<<(int)(BSD / 2048), 256, 0, stream>>>(query, qin, (int)BSD);
    cvt_f32_bf16<<<(int)(BSD / 2048), 256, 0, stream>>>(key,   kin, (int)BSD);
    cvt_f32_bf16<<<(int)(BSD / 2048), 256, 0, stream>>>(value, vin, (int)BSD);

    // 2. QKV projections (256x128 co-resident GEMM; q pre-scaled for exp2)
    const int nwg = ((BB * SS) / 256) * (DD / 128);   // 512, % 8 == 0
    gemm_bt<false><<<nwg, 512, 0, stream>>>(qin, wqb, bq, qbuf, BB * SS, DD, DD, QSCALE);
    gemm_bt<false><<<nwg, 512, 0, stream>>>(kin, wkb, bk, kbuf, BB * SS, DD, DD, 1.0f);
    gemm_bt<false><<<nwg, 512, 0, stream>>>(vin, wvb, bv, vbuf, BB * SS, DD, DD, 1.0f);

    // 3. kp/vp = k^T E, v^T F — E/F read directly as f32 (fused transpose+cvt)
    hipMemsetAsync(kpf, 0, BHDR * 4 * 2, stream);
    kpvp_gemm<<<dim3(SS / 512, HH, BB), 256, 0, stream>>>(kbuf, E, kpf);
    kpvp_gemm<<<dim3(SS / 512, HH, BB), 256, 0, stream>>>(vbuf, F, vpf);

    // 4. kp -> kpT bf16 [B,H,R,DK]; vp -> bf16 [B,H,DK,R]  (kin region dead)
    dim3 tb(64, 4);
    transpose_cvt<<<dim3(RR / 64, DK / 64, BB * HH), tb, 0, stream>>>(kpf, kpt, DK, RR);
    cvt_f32_bf16<<<(int)(BHDR / 2048), 256, 0, stream>>>(vpf, vpbb, (int)BHDR);

    // 5. fused softmax attention (vin region dead -> ctx)
    attn_fused<<<dim3(SS / 1024, HH, BB), 512, 0, stream>>>(qbuf, kpt, vpbb, ctx);

    // 6. output projection -> f32 d_out
    gemm_bt<true><<<nwg, 512, 0, stream>>>(ctx, wob, bo, d_out, BB * SS, DD, DD, 1.0f);
}